// Round 7
// baseline (139.356 us; speedup 1.0000x reference)
//
#include <hip/hip_runtime.h>
#include <hip/hip_bf16.h>
#include <stdint.h>

// Problem constants (fixed shapes from reference: B=4096, D=256, N=2B)
#define NROWS 8192
#define DDIM  256
#define BM    256
#define BN    256
#define BK    32
#define KSTEPS (DDIM / BK)              // 8 K-tiles
#define NTILE (NROWS / BM)              // 32 tile-rows
#define NTRI  (NTILE * (NTILE + 1) / 2) // 528 upper-tri tiles
// TAU = 0.1 -> z = cos/TAU; exp(z-10) = exp2(cos*L2E/TAU - 10*L2E)
// L2E/TAU == 10*L2E == 14.4269504: e = exp2(SCEXP*(cos - 1)), one FMA + one exp.
#define SCEXP 14.4269504088896340736f

// LDS: double-buffered staging uses 64 KB; PADDED to 84 KB on purpose so the
// LDS-implied occupancy is exactly 1 block/CU.
//
// Register-allocator model (fitted to rounds 2-6): HIP __launch_bounds__'s
// 2nd arg is min BLOCKS per CU (CUDA semantics); VGPR cap =
// 512 / wavesPerEU(minBlocks x blockWaves):
//   r2-4: (512,2)/default -> 2 blk x 8 waves -> 4 w/EU -> 128 regs (observed)
//   r5-6: (1024,4) -> 64 waves req -> clamp 8 w/EU ->  64 regs (observed;
//         my "(1024,4)=4 waves/EU" reading was wrong -> acc spilled, 77 MB
//         scratch WRITE_SIZE)
// Fix: (1024,1) -> 1 blk x 16 waves -> 4 w/EU -> 128-reg budget; kernel needs
// ~115 -> fits, zero scratch. 84 KB LDS keeps the occupancy signal consistent.
#define SMEM_BYTES  86016
#define ROW_STRIDE2 18   // 16 partial slots + 2 pad (float2 units)

typedef __attribute__((ext_vector_type(8))) short short8;
typedef __attribute__((ext_vector_type(4))) float f32x4;

typedef const __attribute__((address_space(1))) uint32_t glb_u32;
typedef __attribute__((address_space(3))) uint32_t lds_u32;

__device__ __forceinline__ void load_lds16(const unsigned short* g, unsigned short* l) {
  // 16B per lane, LDS dest = wave-uniform base + lane*16 (HW scatter)
  __builtin_amdgcn_global_load_lds((glb_u32*)g, (lds_u32*)l, 16, 0, 0);
}

__device__ __forceinline__ unsigned short f2bf(float x) {
  __hip_bfloat16 h = __float2bfloat16(x);
  return *reinterpret_cast<unsigned short*>(&h);
}

// Kernel 1: bf16 concat(f) PRE-NORMALIZED (inv-norm folded into operands so
// the GEMM accumulator is the cosine directly), labels, zero S arrays + out.
__global__ void __launch_bounds__(256)
milnce_prep(const float* __restrict__ feat, const float* __restrict__ pos,
            const int* __restrict__ labels, unsigned short* __restrict__ fb,
            int* __restrict__ lab, float* __restrict__ S_all,
            float* __restrict__ S_pos, float* __restrict__ out) {
  const int wave = threadIdx.x >> 6;
  const int lane = threadIdx.x & 63;
  const int row  = blockIdx.x * 4 + wave;   // 2048 blocks -> 8192 rows

  const float* src = (row < 4096) ? (feat + (size_t)row * DDIM)
                                  : (pos + (size_t)(row - 4096) * DDIM);
  float4 v = ((const float4*)src)[lane];    // 4 contiguous fp32 per lane

  float ss = v.x*v.x + v.y*v.y + v.z*v.z + v.w*v.w;
  #pragma unroll
  for (int m = 1; m < 64; m <<= 1) ss += __shfl_xor(ss, m, 64);  // all lanes get sum
  const float inv = 1.0f / sqrtf(ss);

  ushort4 o;
  o.x = f2bf(v.x * inv); o.y = f2bf(v.y * inv);
  o.z = f2bf(v.z * inv); o.w = f2bf(v.w * inv);
  ((ushort4*)(fb + (size_t)row * DDIM))[lane] = o;

  const int tid = blockIdx.x * 256 + threadIdx.x;
  if (tid < NROWS) {
    lab[tid]   = labels[tid & 4095];  // concat duplicates labels
    S_all[tid] = 0.0f;
    S_pos[tid] = 0.0f;
  }
  if (tid == 0) out[0] = 0.0f;
}

// Kernel 2: fused f@f^T (bf16 MFMA) + exp2 masked sums over UPPER-TRI tiles.
// 16 waves (1024 thr), wave grid 4x4, each wave owns 64x64 -> acc[4][4].
// Counted-vmcnt dbuf schedule: stage(kt+1) 2 loads -> vmcnt(2) (kt's 2 loads,
// issued a full K-tile earlier, landed; kt+1's stay in flight) -> barrier ->
// 8x ds_read_b128 -> lgkm(0) -> 16 MFMA -> barrier. Only change vs round 6:
// __launch_bounds__ second arg 4 -> 1 (min BLOCKS per CU, CUDA semantics)
// to get the 128-reg budget (see allocator model above).
__global__ void __launch_bounds__(1024, 1)
milnce_gemm(const unsigned short* __restrict__ fb, const int* __restrict__ lab,
            float* __restrict__ S_all, float* __restrict__ S_pos) {
  __shared__ __align__(16) char smem[SMEM_BYTES];
  unsigned short* lds = (unsigned short*)smem;

  // Diagonal-order tile decode: diagonal d = bj-bi, cum(d) = d*(65-d)/2.
  int t = blockIdx.x;
  int d = (int)((65.0f - sqrtf(4225.0f - 8.0f * (float)t)) * 0.5f);
  while (d * (65 - d) / 2 > t) --d;                 // fp fixups (<=1 iter)
  while ((d + 1) * (64 - d) / 2 <= t) ++d;
  const int rem = t - d * (65 - d) / 2;
  const int bi = rem, bj = rem + d;

  const int tid  = threadIdx.x;
  const int wave = tid >> 6;
  const int lane = tid & 63;
  const int quad = lane >> 4;
  const int l15  = lane & 15;
  const int wm   = wave >> 2;   // 4 row-quarters of 64
  const int wn   = wave & 3;    // 4 col-quarters of 64
  const int rowBase = bi * BM;
  const int colBase = bj * BN;

  f32x4 acc[4][4];
  #pragma unroll
  for (int i = 0; i < 4; ++i)
    #pragma unroll
    for (int j = 0; j < 4; ++j) acc[i][j] = (f32x4){0.f, 0.f, 0.f, 0.f};

  // Staging (per K-tile, per matrix): 1024 slots of 16B (256 rows x 4 octets),
  // one slot per thread. Slot s: p = s>>3, j' = (s&7)^(p&7), r = 2p + (j'>>2),
  // o = j'&3  -- XOR swizzle pre-applied on the GLOBAL source address so the
  // LDS dest stays linear (global_load_lds requirement), and ds_read_b128 of
  // a 16-lane column slice hits 8 distinct bank-quads (2-way = free).
  const unsigned short *gA0, *gB0;
  {
    const int p0 = tid >> 3, j0 = (tid & 7) ^ (p0 & 7);
    const int r0 = p0 * 2 + (j0 >> 2), o0 = j0 & 3;
    gA0 = fb + (size_t)(rowBase + r0) * DDIM + o0 * 8;
    gB0 = fb + (size_t)(colBase + r0) * DDIM + o0 * 8;
  }
  const int dst0 = (wave * 64) * 8;   // wave-uniform dest (shorts), slot=lane

  auto stage = [&](int kt1, int bufS) {
    load_lds16(gA0 + kt1 * BK, lds + bufS + dst0);
    load_lds16(gB0 + kt1 * BK, lds + bufS + 8192 + dst0);
  };

  // Reader: row r, octet q -> slot16 = (r>>1)*8 + (((r&1)*4+q)^((r>>1)&7)).
  // (r>>1)&7 == (l15>>1)&7 since wm*64 / wn*64 row bases are 0 mod 16.
  const int key  = ((l15 & 1) * 4 + quad) ^ ((l15 >> 1) & 7);
  const int aOff = (wm * 32 + (l15 >> 1)) * 64 + key * 8;          // shorts
  const int bOff = 8192 + (wn * 32 + (l15 >> 1)) * 64 + key * 8;   // shorts

  // Prologue: stage kt=0 into buffer 0 (waited at kt=0 top, one-time stall).
  stage(0, 0);

  #pragma unroll
  for (int kt = 0; kt < KSTEPS; ++kt) {
    const int bufS  = (kt & 1) * 16384;
    const int nbufS = bufS ^ 16384;
    const unsigned short* As = lds + bufS;

    if (kt + 1 < KSTEPS) {
      stage(kt + 1, nbufS);
      // kt's 2 loads (issued one full K-tile ago) landed; kt+1's stay in flight
      asm volatile("s_waitcnt vmcnt(2)" ::: "memory");
    } else {
      asm volatile("s_waitcnt vmcnt(0)" ::: "memory");
    }
    asm volatile("s_barrier" ::: "memory");    // buf[cur] now valid for all waves

    short8 a[4], b[4];
    #pragma unroll
    for (int mi = 0; mi < 4; ++mi) a[mi] = *(const short8*)&As[aOff + mi * 512];
    #pragma unroll
    for (int ni = 0; ni < 4; ++ni) b[ni] = *(const short8*)&As[bOff + ni * 512];
    asm volatile("s_waitcnt lgkmcnt(0)" ::: "memory");
    __builtin_amdgcn_sched_barrier(0);
    __builtin_amdgcn_s_setprio(1);
    #pragma unroll
    for (int mi = 0; mi < 4; ++mi)
      #pragma unroll
      for (int ni = 0; ni < 4; ++ni)
        acc[mi][ni] = __builtin_amdgcn_mfma_f32_16x16x32_bf16(a[mi], b[ni], acc[mi][ni], 0, 0, 0);
    __builtin_amdgcn_s_setprio(0);
    // reads of buf[cur] drained (lgkm above); after this barrier the next
    // iteration's stage may overwrite it
    asm volatile("s_barrier" ::: "memory");
  }
  __syncthreads();   // staging LDS dead; safe to alias with epilogue scratch

  // Epilogue. C/D layout (16x16x32): col = lane&15, row = quad*4 + reg.
  // acc is the cosine directly: e = exp2(SCEXP*acc - SCEXP) == exp(z - 10);
  // the -10 shift cancels in log(S_all) - log(S_pos).
  float2* rowAP = (float2*)smem;   // [256 rows][18 float2]

  int cl[4], colg[4];
  #pragma unroll
  for (int ni = 0; ni < 4; ++ni) {
    colg[ni] = colBase + wn * 64 + ni * 16 + l15;
    cl[ni]   = lab[colg[ni]];
  }

  const bool offdiag = (bi != bj);
  float2 capk[4] = {{0.f,0.f},{0.f,0.f},{0.f,0.f},{0.f,0.f}};

  #pragma unroll
  for (int mi = 0; mi < 4; ++mi) {
    const int rbase = wm * 64 + mi * 16 + quad * 4;
    const int4 rl4 = *(const int4*)&lab[rowBase + rbase];
    #pragma unroll
    for (int r = 0; r < 4; ++r) {
      const int rl = (r == 0) ? rl4.x : (r == 1) ? rl4.y : (r == 2) ? rl4.z : rl4.w;
      const int rowg = rowBase + rbase + r;
      float sx = 0.f, sy = 0.f;
      #pragma unroll
      for (int ni = 0; ni < 4; ++ni) {
        float e = exp2f(__builtin_fmaf(acc[mi][ni][r], SCEXP, -SCEXP));
        if (!offdiag && rowg == colg[ni]) e = 0.f;   // mask diagonal entries
        float ep = (rl == cl[ni]) ? e : 0.f;
        capk[ni].x += e; capk[ni].y += ep;
        sx += e; sy += ep;
      }
      if (offdiag) {
        // pre-reduce across l15 (masks 4,8): lane l15<4 holds the sum over
        // its l15-mod-4 class (4 lanes x 4 ni = 16 of this wave's 64 cols).
        sx += __shfl_xor(sx, 4, 64); sx += __shfl_xor(sx, 8, 64);
        sy += __shfl_xor(sy, 4, 64); sy += __shfl_xor(sy, 8, 64);
        if (l15 < 4)
          rowAP[(rbase + r) * ROW_STRIDE2 + wn * 4 + l15] = make_float2(sx, sy);
      }
    }
  }

  // Column commit: quad-reduce (masks 16,32) -> coalesced atomics. The 4 wm
  // waves of each wn each add their 64-row partial; atomics accumulate.
  #pragma unroll
  for (int ni = 0; ni < 4; ++ni) {
    float x = capk[ni].x, y = capk[ni].y;
    x += __shfl_xor(x, 16, 64); x += __shfl_xor(x, 32, 64);
    y += __shfl_xor(y, 16, 64); y += __shfl_xor(y, 32, 64);
    if (quad == 0) {
      atomicAdd(&S_all[colg[ni]], x);
      atomicAdd(&S_pos[colg[ni]], y);
    }
  }

  __syncthreads();

  if (offdiag && tid < 256) {
    // Row commit (== skipped transposed tile's columns): sum 16 partials.
    const float2* rp = rowAP + tid * ROW_STRIDE2;
    float sx = 0.f, sy = 0.f;
    #pragma unroll
    for (int i = 0; i < 16; ++i) { sx += rp[i].x; sy += rp[i].y; }
    atomicAdd(&S_all[rowBase + tid], sx);
    atomicAdd(&S_pos[rowBase + tid], sy);
  }
}

// Kernel 3: loss = sum_i log(S_all[i]) - log(S_pos[i])  (the +10 shifts cancel).
// 32 blocks, one element per thread, one atomic per block; out zeroed by prep.
__global__ void __launch_bounds__(256)
milnce_final(const float* __restrict__ S_all, const float* __restrict__ S_pos,
             float* __restrict__ out) {
  const int i = blockIdx.x * 256 + threadIdx.x;   // 32*256 == NROWS
  float s = logf(S_all[i]) - logf(S_pos[i]);
  #pragma unroll
  for (int m = 1; m < 64; m <<= 1) s += __shfl_xor(s, m, 64);
  __shared__ float red[4];
  if ((threadIdx.x & 63) == 0) red[threadIdx.x >> 6] = s;
  __syncthreads();
  if (threadIdx.x == 0) atomicAdd(out, (red[0] + red[1]) + (red[2] + red[3]));
}

extern "C" void kernel_launch(void* const* d_in, const int* in_sizes, int n_in,
                              void* d_out, int out_size, void* d_ws, size_t ws_size,
                              hipStream_t stream) {
  const float* feat   = (const float*)d_in[0];
  const float* pos    = (const float*)d_in[1];
  const int*   labels = (const int*)d_in[2];

  char* ws = (char*)d_ws;
  unsigned short* fb    = (unsigned short*)ws;                       // 4 MB bf16 normalized concat
  int*            lab   = (int*)  (ws + 4u * 1024 * 1024);           // 32 KB
  float*          S_all = (float*)(ws + 4u * 1024 * 1024 + 32 * 1024);
  float*          S_pos = (float*)(ws + 4u * 1024 * 1024 + 64 * 1024);
  float*          out   = (float*)d_out;

  hipLaunchKernelGGL(milnce_prep, dim3(NROWS / 4), dim3(256), 0, stream,
                     feat, pos, labels, fb, lab, S_all, S_pos, out);
  hipLaunchKernelGGL(milnce_gemm, dim3(NTRI), dim3(1024), 0, stream,
                     fb, lab, S_all, S_pos);
  hipLaunchKernelGGL(milnce_final, dim3(32), dim3(256), 0, stream,
                     S_all, S_pos, out);
}

// Round 8
// 116.535 us; speedup vs baseline: 1.1958x; 1.1958x over previous
//
#include <hip/hip_runtime.h>
#include <hip/hip_bf16.h>
#include <stdint.h>

// Problem constants (fixed shapes from reference: B=4096, D=256, N=2B)
#define NROWS 8192
#define DDIM  256
#define BM    128                        // tile rows
#define BN    256                        // tile cols
#define BK    32
#define KSTEPS (DDIM / BK)               // 8 K-tiles
#define NBI   (NROWS / BM)               // 64 row-tiles
#define NBJ   (NROWS / BN)               // 32 col-tiles
// Blocks: all (bi,bj) with bi <= 2*bj+1  ->  sum_{j}(2j+2) = 1056.
// Strictly-above tiles: bi <= 2bj-1. Straddling (contain diagonal): bi>>1==bj,
// masked to strictly-upper (col>row). Every computed element e contributes to
// S[col] (col-commit) AND S[row] (row-commit, the mirror) exactly once.
#define NBLK  1056
// TAU = 0.1 -> z = cos/TAU; exp(z-10) = exp2(cos*L2E/TAU - 10*L2E)
// L2E/TAU == 10*L2E == 14.4269504: e = exp2(SCEXP*(cos - 1)), one FMA + one exp.
#define SCEXP 14.4269504088896340736f

// LDS: dbuf staging, per buffer A(8KB)+B(16KB)=24KB -> 48KB; padded to 56KB.
//
// Register-allocator model (MEASURED, rounds 2-7, invariant to launch_bounds /
// waves_per_eu / LDS pads): VGPR cap = 65536 / blockThreads (two blocks' worth
// of the CU register file): 512thr -> 128 regs (r2-4), 1024thr -> 64 (r5-7).
// Attributes never moved it (identical counters r5/r6/r7). So: design to the
// cap. 512 threads, wave tile 64x64 (acc[4][4]=64 regs, total ~105 < 128).
// 56KB keeps the LDS-implied occupancy at the same 2 blocks/CU.
#define SMEM_BYTES  57344
#define BUF_SHORTS  12288   // 24KB per buffer, in shorts
#define B_OFF       4096    // B-tile offset within buffer (shorts)
#define ROW_STRIDE2 18      // rowAP: 16 partial slots + 2 pad (float2 units)

typedef __attribute__((ext_vector_type(8))) short short8;
typedef __attribute__((ext_vector_type(4))) float f32x4;

typedef const __attribute__((address_space(1))) uint32_t glb_u32;
typedef __attribute__((address_space(3))) uint32_t lds_u32;

__device__ __forceinline__ void load_lds16(const unsigned short* g, unsigned short* l) {
  // 16B per lane, LDS dest = wave-uniform base + lane*16 (HW scatter)
  __builtin_amdgcn_global_load_lds((glb_u32*)g, (lds_u32*)l, 16, 0, 0);
}

__device__ __forceinline__ unsigned short f2bf(float x) {
  __hip_bfloat16 h = __float2bfloat16(x);
  return *reinterpret_cast<unsigned short*>(&h);
}

// Kernel 1: bf16 concat(f) PRE-NORMALIZED (inv-norm folded into operands so
// the GEMM accumulator is the cosine directly), labels, zero S arrays + out.
__global__ void __launch_bounds__(256)
milnce_prep(const float* __restrict__ feat, const float* __restrict__ pos,
            const int* __restrict__ labels, unsigned short* __restrict__ fb,
            int* __restrict__ lab, float* __restrict__ S_all,
            float* __restrict__ S_pos, float* __restrict__ out) {
  const int wave = threadIdx.x >> 6;
  const int lane = threadIdx.x & 63;
  const int row  = blockIdx.x * 4 + wave;   // 2048 blocks -> 8192 rows

  const float* src = (row < 4096) ? (feat + (size_t)row * DDIM)
                                  : (pos + (size_t)(row - 4096) * DDIM);
  float4 v = ((const float4*)src)[lane];    // 4 contiguous fp32 per lane

  float ss = v.x*v.x + v.y*v.y + v.z*v.z + v.w*v.w;
  #pragma unroll
  for (int m = 1; m < 64; m <<= 1) ss += __shfl_xor(ss, m, 64);  // all lanes get sum
  const float inv = 1.0f / sqrtf(ss);

  ushort4 o;
  o.x = f2bf(v.x * inv); o.y = f2bf(v.y * inv);
  o.z = f2bf(v.z * inv); o.w = f2bf(v.w * inv);
  ((ushort4*)(fb + (size_t)row * DDIM))[lane] = o;

  const int tid = blockIdx.x * 256 + threadIdx.x;
  if (tid < NROWS) {
    lab[tid]   = labels[tid & 4095];  // concat duplicates labels
    S_all[tid] = 0.0f;
    S_pos[tid] = 0.0f;
  }
  if (tid == 0) out[0] = 0.0f;
}

// Kernel 2: fused f@f^T (bf16 MFMA) + exp2 masked sums, 128x256 tiles over the
// strictly-upper triangle (straddling tiles masked to col>row). 8 waves (512
// thr), wave grid 2x4, each wave 64x64 -> acc[4][4] = 64 regs; fits the
// MEASURED 128-reg cap for 512-thread blocks with ~20 regs of headroom.
// Counted-vmcnt dbuf K-loop (verified body from r5): stage(kt+1) 3 loads ->
// vmcnt(3) (kt's 3 loads, issued a full K-tile earlier, landed) -> barrier ->
// 8x ds_read_b128 -> lgkm(0) -> 16 MFMA -> barrier.
__global__ void __launch_bounds__(512)
milnce_gemm(const unsigned short* __restrict__ fb, const int* __restrict__ lab,
            float* __restrict__ S_all, float* __restrict__ S_pos) {
  __shared__ __align__(16) char smem[SMEM_BYTES];
  unsigned short* lds = (unsigned short*)smem;

  // Decode t -> (bi, bj): cum(j) = j*(j+1); j = floor((-1+sqrt(1+4t))/2).
  int t = blockIdx.x;
  int j = (int)((-1.0f + sqrtf(1.0f + 4.0f * (float)t)) * 0.5f);
  while ((j + 1) * (j + 2) <= t) ++j;                // fp fixups (<=1 iter)
  while (j * (j + 1) > t) --j;
  const int bi = t - j * (j + 1), bj = j;

  const int tid  = threadIdx.x;
  const int wave = tid >> 6;
  const int lane = tid & 63;
  const int quad = lane >> 4;
  const int l15  = lane & 15;
  const int wm   = wave >> 2;   // 2 row-halves of 64 (128 rows)
  const int wn   = wave & 3;    // 4 col-quarters of 64 (256 cols)
  const int rowBase = bi * BM;
  const int colBase = bj * BN;
  const bool straddle = ((bi >> 1) == bj);   // tile contains the diagonal

  f32x4 acc[4][4];
  #pragma unroll
  for (int i = 0; i < 4; ++i)
    #pragma unroll
    for (int j2 = 0; j2 < 4; ++j2) acc[i][j2] = (f32x4){0.f, 0.f, 0.f, 0.f};

  // Staging slots (16B each): A = 512 slots (128 rows x 4 octets), B = 1024
  // slots (256 rows x 4 octets). Slot s: p = s>>3, j' = (s&7)^(p&7),
  // r = 2p + (j'>>2), o = j'&3 -- XOR swizzle pre-applied on the GLOBAL source
  // so the LDS dest stays linear (global_load_lds requirement); ds_read_b128
  // column slices then hit distinct bank-quads (conflict-free, r5-verified).
  // Wave w stages: A slot w*64+lane; B slots w*128+lane, w*128+64+lane.
  const unsigned short *gA0, *gB0, *gB1;
  {
    const int sA = wave * 64 + lane;
    const int pA = sA >> 3, jA = (sA & 7) ^ (pA & 7);
    gA0 = fb + (size_t)(rowBase + pA * 2 + (jA >> 2)) * DDIM + (jA & 3) * 8;
    const int s0 = wave * 128 + lane;
    const int p0 = s0 >> 3, j0 = (s0 & 7) ^ (p0 & 7);
    gB0 = fb + (size_t)(colBase + p0 * 2 + (j0 >> 2)) * DDIM + (j0 & 3) * 8;
    const int s1 = wave * 128 + 64 + lane;
    const int p1 = s1 >> 3, j1 = (s1 & 7) ^ (p1 & 7);
    gB1 = fb + (size_t)(colBase + p1 * 2 + (j1 >> 2)) * DDIM + (j1 & 3) * 8;
  }
  const int dstA  = wave * 512;                 // shorts, wave-uniform
  const int dstB0 = B_OFF + wave * 1024;
  const int dstB1 = dstB0 + 512;

  auto stage = [&](int kt1, int bufS) {
    load_lds16(gA0 + kt1 * BK, lds + bufS + dstA);
    load_lds16(gB0 + kt1 * BK, lds + bufS + dstB0);
    load_lds16(gB1 + kt1 * BK, lds + bufS + dstB1);
  };

  // Reader: row r, octet q -> slot16 = (r>>1)*8 + (((r&1)*4+q)^((r>>1)&7)).
  // (r>>1)&7 == (l15>>1)&7 since wm*64 / wn*64 / mi*16 keep (r>>1) = 0 mod 8.
  const int key  = ((l15 & 1) * 4 + quad) ^ ((l15 >> 1) & 7);
  const int aOff = (wm * 32 + (l15 >> 1)) * 64 + key * 8;           // shorts
  const int bOff = B_OFF + (wn * 32 + (l15 >> 1)) * 64 + key * 8;   // shorts

  // Prologue: stage kt=0 into buffer 0 (waited at kt=0 top, one-time stall).
  stage(0, 0);

  #pragma unroll
  for (int kt = 0; kt < KSTEPS; ++kt) {
    const int bufS  = (kt & 1) * BUF_SHORTS;
    const int nbufS = bufS ^ BUF_SHORTS;
    const unsigned short* As = lds + bufS;

    if (kt + 1 < KSTEPS) {
      stage(kt + 1, nbufS);
      // kt's 3 loads (issued one full K-tile ago) landed; kt+1's stay in flight
      asm volatile("s_waitcnt vmcnt(3)" ::: "memory");
    } else {
      asm volatile("s_waitcnt vmcnt(0)" ::: "memory");
    }
    asm volatile("s_barrier" ::: "memory");    // buf[cur] now valid for all waves

    short8 a[4], b[4];
    #pragma unroll
    for (int mi = 0; mi < 4; ++mi) a[mi] = *(const short8*)&As[aOff + mi * 512];
    #pragma unroll
    for (int ni = 0; ni < 4; ++ni) b[ni] = *(const short8*)&As[bOff + ni * 512];
    asm volatile("s_waitcnt lgkmcnt(0)" ::: "memory");
    __builtin_amdgcn_sched_barrier(0);
    __builtin_amdgcn_s_setprio(1);
    #pragma unroll
    for (int mi = 0; mi < 4; ++mi)
      #pragma unroll
      for (int ni = 0; ni < 4; ++ni)
        acc[mi][ni] = __builtin_amdgcn_mfma_f32_16x16x32_bf16(a[mi], b[ni], acc[mi][ni], 0, 0, 0);
    __builtin_amdgcn_s_setprio(0);
    // reads of buf[cur] drained (lgkm above); after this barrier the next
    // iteration's stage may overwrite it
    asm volatile("s_barrier" ::: "memory");
  }
  __syncthreads();   // staging LDS dead; safe to alias with epilogue scratch

  // Epilogue. C/D layout (16x16x32): col = lane&15, row = quad*4 + reg.
  // acc is the cosine directly: e = exp2(SCEXP*acc - SCEXP) == exp(z - 10);
  // the -10 shift cancels in log(S_all) - log(S_pos). Straddling tiles mask
  // col<=row (keeps strictly-upper only); every element then commits to both
  // its column (direct) and row (mirror of the never-computed transpose).
  float2* rowAP = (float2*)smem;   // [128 rows][18 float2]

  int cl[4], colg[4];
  #pragma unroll
  for (int ni = 0; ni < 4; ++ni) {
    colg[ni] = colBase + wn * 64 + ni * 16 + l15;
    cl[ni]   = lab[colg[ni]];
  }

  float2 capk[4] = {{0.f,0.f},{0.f,0.f},{0.f,0.f},{0.f,0.f}};

  #pragma unroll
  for (int mi = 0; mi < 4; ++mi) {
    const int rbase = wm * 64 + mi * 16 + quad * 4;
    const int4 rl4 = *(const int4*)&lab[rowBase + rbase];
    #pragma unroll
    for (int r = 0; r < 4; ++r) {
      const int rl = (r == 0) ? rl4.x : (r == 1) ? rl4.y : (r == 2) ? rl4.z : rl4.w;
      const int rowg = rowBase + rbase + r;
      float sx = 0.f, sy = 0.f;
      #pragma unroll
      for (int ni = 0; ni < 4; ++ni) {
        float e = exp2f(__builtin_fmaf(acc[mi][ni][r], SCEXP, -SCEXP));
        if (straddle && colg[ni] <= rowg) e = 0.f;   // strictly-upper only
        float ep = (rl == cl[ni]) ? e : 0.f;
        capk[ni].x += e; capk[ni].y += ep;
        sx += e; sy += ep;
      }
      // pre-reduce across l15 (masks 4,8): lane l15<4 holds the sum over its
      // l15-mod-4 class (4 lanes x 4 ni = 16 of this wave's 64 columns).
      sx += __shfl_xor(sx, 4, 64); sx += __shfl_xor(sx, 8, 64);
      sy += __shfl_xor(sy, 4, 64); sy += __shfl_xor(sy, 8, 64);
      if (l15 < 4)
        rowAP[(rbase + r) * ROW_STRIDE2 + wn * 4 + l15] = make_float2(sx, sy);
    }
  }

  // Column commit: quad-reduce (masks 16,32) -> coalesced atomics. Both wm
  // waves of each wn add their 64-row partials; atomics accumulate.
  #pragma unroll
  for (int ni = 0; ni < 4; ++ni) {
    float x = capk[ni].x, y = capk[ni].y;
    x += __shfl_xor(x, 16, 64); x += __shfl_xor(x, 32, 64);
    y += __shfl_xor(y, 16, 64); y += __shfl_xor(y, 32, 64);
    if (quad == 0) {
      atomicAdd(&S_all[colg[ni]], x);
      atomicAdd(&S_pos[colg[ni]], y);
    }
  }

  __syncthreads();

  if (tid < BM) {
    // Row commit (mirror contributions): sum 16 partials (4 wn x 4 classes).
    const float2* rp = rowAP + tid * ROW_STRIDE2;
    float sx = 0.f, sy = 0.f;
    #pragma unroll
    for (int i = 0; i < 16; ++i) { sx += rp[i].x; sy += rp[i].y; }
    atomicAdd(&S_all[rowBase + tid], sx);
    atomicAdd(&S_pos[rowBase + tid], sy);
  }
}

// Kernel 3: loss = sum_i log(S_all[i]) - log(S_pos[i])  (the +10 shifts cancel).
// 32 blocks, one element per thread, one atomic per block; out zeroed by prep.
__global__ void __launch_bounds__(256)
milnce_final(const float* __restrict__ S_all, const float* __restrict__ S_pos,
             float* __restrict__ out) {
  const int i = blockIdx.x * 256 + threadIdx.x;   // 32*256 == NROWS
  float s = logf(S_all[i]) - logf(S_pos[i]);
  #pragma unroll
  for (int m = 1; m < 64; m <<= 1) s += __shfl_xor(s, m, 64);
  __shared__ float red[4];
  if ((threadIdx.x & 63) == 0) red[threadIdx.x >> 6] = s;
  __syncthreads();
  if (threadIdx.x == 0) atomicAdd(out, (red[0] + red[1]) + (red[2] + red[3]));
}

extern "C" void kernel_launch(void* const* d_in, const int* in_sizes, int n_in,
                              void* d_out, int out_size, void* d_ws, size_t ws_size,
                              hipStream_t stream) {
  const float* feat   = (const float*)d_in[0];
  const float* pos    = (const float*)d_in[1];
  const int*   labels = (const int*)d_in[2];

  char* ws = (char*)d_ws;
  unsigned short* fb    = (unsigned short*)ws;                       // 4 MB bf16 normalized concat
  int*            lab   = (int*)  (ws + 4u * 1024 * 1024);           // 32 KB
  float*          S_all = (float*)(ws + 4u * 1024 * 1024 + 32 * 1024);
  float*          S_pos = (float*)(ws + 4u * 1024 * 1024 + 64 * 1024);
  float*          out   = (float*)d_out;

  hipLaunchKernelGGL(milnce_prep, dim3(NROWS / 4), dim3(256), 0, stream,
                     feat, pos, labels, fb, lab, S_all, S_pos, out);
  hipLaunchKernelGGL(milnce_gemm, dim3(NBLK), dim3(512), 0, stream,
                     fb, lab, S_all, S_pos);
  hipLaunchKernelGGL(milnce_final, dim3(32), dim3(256), 0, stream,
                     S_all, S_pos, out);
}